// Round 1
// baseline (789.142 us; speedup 1.0000x reference)
//
#include <hip/hip_runtime.h>

// Problem constants (from reference): B=4, N=4096, E=2048, C_IN=C_OUT=64
#define B_ 4
#define N_ 4096
#define E_ 2048
#define C_ 64

// ---------------------------------------------------------------------------
// K1: xt[b,n,o] = sum_k x[b,n,k] * theta[k,o]
// grid = B*N*64/256, block = 256. theta reads coalesced across o; x broadcast.
// ---------------------------------------------------------------------------
__global__ __launch_bounds__(256) void k_transform(
    const float* __restrict__ x, const float* __restrict__ theta,
    float* __restrict__ xt) {
  int idx = blockIdx.x * 256 + threadIdx.x;  // [0, B*N*64)
  int o = idx & 63;
  int bn = idx >> 6;
  const float* xr = x + (size_t)bn * 64;
  float acc = 0.f;
#pragma unroll
  for (int k = 0; k < 64; ++k) acc += xr[k] * theta[k * 64 + o];
  xt[idx] = acc;
}

// ---------------------------------------------------------------------------
// K2: deg_e[b,e] = sum_n H[b,n,e]  (exact: H is 0/1, partial atomics exact)
// grid = B * (E/256) * (N/64) = 2048 blocks of 256. Coalesced rows of 256 e.
// ---------------------------------------------------------------------------
__global__ __launch_bounds__(256) void k_deg_e(
    const float* __restrict__ H, float* __restrict__ deg_e) {
  int bx = blockIdx.x;
  int ec = bx & 7;          // E/256 = 8 chunks
  int nc = (bx >> 3) & 63;  // N/64 = 64 chunks
  int b  = bx >> 9;
  int e = ec * 256 + threadIdx.x;
  const float* Hp = H + ((size_t)(b * N_ + nc * 64) * E_ + e);
  float s = 0.f;
#pragma unroll 8
  for (int i = 0; i < 64; ++i) s += Hp[(size_t)i * E_];
  atomicAdd(&deg_e[b * E_ + e], s);
}

// ---------------------------------------------------------------------------
// K3: deg_n[b,n] = sum_e H[b,n,e]. One wave per row; coalesced; shuffle-reduce.
// grid = B*N/4 blocks of 256 (4 waves).
// ---------------------------------------------------------------------------
__global__ __launch_bounds__(256) void k_deg_n(
    const float* __restrict__ H, float* __restrict__ deg_n) {
  int widx = threadIdx.x >> 6;
  int lane = threadIdx.x & 63;
  int rid = blockIdx.x * 4 + widx;  // b*N + n
  const float* Hp = H + (size_t)rid * E_ + lane;
  float s = 0.f;
#pragma unroll
  for (int k = 0; k < E_ / 64; ++k) s += Hp[k * 64];
  for (int off = 32; off > 0; off >>= 1) s += __shfl_down(s, off, 64);
  if (lane == 0) deg_n[rid] = s;
}

// ---------------------------------------------------------------------------
// K4: he_raw[b,e,o] += sum_n H[b,n,e] * xt[b,n,o]
// Wave handles 8 consecutive e (acc[8]), lane = o. N split 4 ways (occupancy:
// 4096 waves = 4/SIMD); partials land via atomicAdd (he zeroed by memset).
// Per n: 2 broadcast float4 H loads + 1 coalesced xt load + 8 fmac.
// grid = 1024 blocks of 256.
// ---------------------------------------------------------------------------
__global__ __launch_bounds__(256) void k_edge(
    const float* __restrict__ H, const float* __restrict__ xt,
    float* __restrict__ he) {
  int widx = threadIdx.x >> 6;
  int lane = threadIdx.x & 63;  // o
  int gw = blockIdx.x * 4 + widx;           // [0, 4096)
  int t = gw & 255;                         // e-tile, E/8 = 256
  int s = (gw >> 8) & 3;                    // n-split
  int b = gw >> 10;
  int e0 = t * 8;
  int n0 = s * (N_ / 4);
  float acc[8];
#pragma unroll
  for (int j = 0; j < 8; ++j) acc[j] = 0.f;
  const float* xtp = xt + (((size_t)(b * N_ + n0)) << 6) + lane;
  const float* Hp = H + ((size_t)(b * N_ + n0) * E_) + e0;
#pragma unroll 4
  for (int n = 0; n < N_ / 4; ++n) {
    float4 ha = *(const float4*)(Hp);
    float4 hb = *(const float4*)(Hp + 4);
    float xv = *xtp;
    acc[0] += ha.x * xv; acc[1] += ha.y * xv;
    acc[2] += ha.z * xv; acc[3] += ha.w * xv;
    acc[4] += hb.x * xv; acc[5] += hb.y * xv;
    acc[6] += hb.z * xv; acc[7] += hb.w * xv;
    Hp += E_; xtp += 64;
  }
  float* hep = he + (((size_t)(b * E_ + e0)) << 6) + lane;
#pragma unroll
  for (int j = 0; j < 8; ++j) atomicAdd(hep + (j << 6), acc[j]);
}

// ---------------------------------------------------------------------------
// K5: he[b,e,o] /= deg_e[b,e]
// ---------------------------------------------------------------------------
__global__ __launch_bounds__(256) void k_he_norm(
    float* __restrict__ he, const float* __restrict__ deg_e) {
  int idx = blockIdx.x * 256 + threadIdx.x;  // [0, B*E*64)
  he[idx] = he[idx] / deg_e[idx >> 6];
}

// ---------------------------------------------------------------------------
// K6: out[b,n,o] = (sum_e H[b,n,e]*he[b,e,o]) / deg_n[b,n] + bias[o]
// Wave handles 8 rows n (acc[8]), lane = o. Loop e in steps of 4:
// 8 broadcast float4 H loads + 4 coalesced he loads + 32 fmac.
// grid = 512 blocks of 256 (2048 waves).
// ---------------------------------------------------------------------------
__global__ __launch_bounds__(256) void k_node(
    const float* __restrict__ H, const float* __restrict__ he,
    const float* __restrict__ deg_n, const float* __restrict__ bias,
    float* __restrict__ out) {
  int widx = threadIdx.x >> 6;
  int lane = threadIdx.x & 63;  // o
  int gw = blockIdx.x * 4 + widx;  // [0, 2048)
  int t = gw & 511;                // n-tile, N/8 = 512
  int b = gw >> 9;
  int n0 = t * 8;
  float acc[8];
#pragma unroll
  for (int r = 0; r < 8; ++r) acc[r] = 0.f;
  const float* Hp = H + ((size_t)(b * N_ + n0) * E_);
  const float* hep = he + (((size_t)(b * E_)) << 6) + lane;
#pragma unroll 2
  for (int e = 0; e < E_; e += 4) {
    float4 h4[8];
#pragma unroll
    for (int r = 0; r < 8; ++r)
      h4[r] = *(const float4*)(Hp + (size_t)r * E_ + e);
    float hv0 = hep[(size_t)(e + 0) << 6];
    float hv1 = hep[(size_t)(e + 1) << 6];
    float hv2 = hep[(size_t)(e + 2) << 6];
    float hv3 = hep[(size_t)(e + 3) << 6];
#pragma unroll
    for (int r = 0; r < 8; ++r) {
      acc[r] += h4[r].x * hv0;
      acc[r] += h4[r].y * hv1;
      acc[r] += h4[r].z * hv2;
      acc[r] += h4[r].w * hv3;
    }
  }
  float bv = bias[lane];
#pragma unroll
  for (int r = 0; r < 8; ++r) {
    float dn = deg_n[b * N_ + n0 + r];
    out[(((size_t)(b * N_ + n0 + r)) << 6) + lane] = acc[r] / dn + bv;
  }
}

extern "C" void kernel_launch(void* const* d_in, const int* in_sizes, int n_in,
                              void* d_out, int out_size, void* d_ws, size_t ws_size,
                              hipStream_t stream) {
  const float* x     = (const float*)d_in[0];
  const float* H     = (const float*)d_in[1];
  const float* theta = (const float*)d_in[2];
  const float* bias  = (const float*)d_in[3];
  float* out = (float*)d_out;

  // ws layout (floats): xt[B*N*64] | he[B*E*64] | deg_e[B*E] | deg_n[B*N]
  float* ws    = (float*)d_ws;
  float* xt    = ws;
  float* he    = xt + (size_t)B_ * N_ * C_;
  float* deg_e = he + (size_t)B_ * E_ * C_;
  float* deg_n = deg_e + (size_t)B_ * E_;
  // total: (1048576 + 524288 + 8192 + 16384)*4 B ~= 6.4 MB

  // zero the atomic accumulation targets (he and deg_e are adjacent)
  hipMemsetAsync(he, 0, ((size_t)B_ * E_ * C_ + (size_t)B_ * E_) * sizeof(float),
                 stream);

  k_transform<<<(B_ * N_ * C_) / 256, 256, 0, stream>>>(x, theta, xt);
  k_deg_e<<<B_ * (E_ / 256) * (N_ / 64), 256, 0, stream>>>(H, deg_e);
  k_deg_n<<<(B_ * N_) / 4, 256, 0, stream>>>(H, deg_n);
  k_edge<<<(B_ * (E_ / 8) * 4) / 4, 256, 0, stream>>>(H, xt, he);
  k_he_norm<<<(B_ * E_ * C_) / 256, 256, 0, stream>>>(he, deg_e);
  k_node<<<(B_ * (N_ / 8)) / 4, 256, 0, stream>>>(H, he, deg_n, bias, out);
}

// Round 2
// 296.527 us; speedup vs baseline: 2.6613x; 2.6613x over previous
//
#include <hip/hip_runtime.h>

// B=4, N=4096, E=2048, C=64. Two bf16 MFMA GEMMs + prep/transform/normalize.
#define B_ 4
#define N_ 4096
#define E_ 2048

typedef __attribute__((ext_vector_type(8))) short short8;   // 8 bf16 (4 VGPRs)
typedef __attribute__((ext_vector_type(4))) float float4v;  // MFMA C/D

// round-to-nearest-even f32 -> bf16 bits
static __device__ __forceinline__ unsigned short f2bf(float f) {
  union { float f; unsigned int u; } v; v.f = f;
  unsigned int r = (v.u + 0x7FFFu + ((v.u >> 16) & 1u)) >> 16;
  return (unsigned short)r;
}

// async global->LDS, 16 B per lane; LDS dest = wave-uniform base + lane*16
static __device__ __forceinline__ void stage16(const void* g, void* l) {
  __builtin_amdgcn_global_load_lds(
      (const __attribute__((address_space(1))) unsigned int*)g,
      (__attribute__((address_space(3))) unsigned int*)l, 16, 0, 0);
}

// ---------------------------------------------------------------------------
// K1: xtT[b][o][n] = bf16( sum_k x[b][n][k] * theta[k][o] )   (transposed!)
// 256 blocks x 256 thr; LDS transpose for coalesced bf16 row writes.
// ---------------------------------------------------------------------------
__global__ __launch_bounds__(256) void k_transform(
    const float* __restrict__ x, const float* __restrict__ theta,
    unsigned short* __restrict__ xtT) {
  __shared__ unsigned short ldsT[64][72];  // [o][n_local], +8 pad
  int t = threadIdx.x;
  int nt = blockIdx.x & 63, b = blockIdx.x >> 6;
  int n0 = nt * 64;
  int o = t & 63, nq = t >> 6;
#pragma unroll 4
  for (int i = 0; i < 16; ++i) {
    int n = n0 + nq * 16 + i;
    const float* xr = x + ((size_t)(b * N_ + n) << 6);
    float acc = 0.f;
#pragma unroll
    for (int k = 0; k < 64; ++k) acc += xr[k] * theta[k * 64 + o];
    ldsT[o][nq * 16 + i] = f2bf(acc);
  }
  __syncthreads();
  int orow = t >> 2, c = (t & 3) * 16;
  unsigned short* dst = xtT + ((size_t)(b * 64 + orow) << 12) + n0 + c;
  *(uint4*)dst = *(const uint4*)&ldsT[orow][c];
  *(uint4*)(dst + 8) = *(const uint4*)&ldsT[orow][c + 8];
}

// ---------------------------------------------------------------------------
// K2: HbfT[b][e][n] = bf16(H[b][n][e])  (transposed, 64 MB) + deg_e atomics.
// 8192 blocks, tile 64n x 64e each. deg_e exact (0/1 sums in fp32).
// ---------------------------------------------------------------------------
__global__ __launch_bounds__(256) void k_prep(
    const float* __restrict__ H, unsigned short* __restrict__ HbfT,
    float* __restrict__ deg_e) {
  __shared__ unsigned short ldsT[64][72];  // [e_local][n_local], +8 pad
  __shared__ float sde[256];
  int t = threadIdx.x;
  int et = blockIdx.x & 31, nt = (blockIdx.x >> 5) & 63, b = blockIdx.x >> 11;
  int e0 = et * 64, n0 = nt * 64;
  int r = t >> 2, c0 = (t & 3) * 16;
  const float* src = H + ((size_t)(b * N_ + n0 + r)) * E_ + e0 + c0;
  float4 f[4];
#pragma unroll
  for (int q = 0; q < 4; ++q) f[q] = *(const float4*)(src + q * 4);
#pragma unroll
  for (int q = 0; q < 4; ++q) {
    ldsT[c0 + q * 4 + 0][r] = f2bf(f[q].x);
    ldsT[c0 + q * 4 + 1][r] = f2bf(f[q].y);
    ldsT[c0 + q * 4 + 2][r] = f2bf(f[q].z);
    ldsT[c0 + q * 4 + 3][r] = f2bf(f[q].w);
  }
  __syncthreads();
  int er = t >> 2, nc = (t & 3) * 16;
  uint4 u0 = *(const uint4*)&ldsT[er][nc];
  uint4 u1 = *(const uint4*)&ldsT[er][nc + 8];
  // bf16 H values are 0x0000 or 0x3F80 -> count via bit 7 of each half
  unsigned int cnt = 0;
  {
    unsigned int wv;
    wv = u0.x; cnt += ((wv >> 7) & 1u) + ((wv >> 23) & 1u);
    wv = u0.y; cnt += ((wv >> 7) & 1u) + ((wv >> 23) & 1u);
    wv = u0.z; cnt += ((wv >> 7) & 1u) + ((wv >> 23) & 1u);
    wv = u0.w; cnt += ((wv >> 7) & 1u) + ((wv >> 23) & 1u);
    wv = u1.x; cnt += ((wv >> 7) & 1u) + ((wv >> 23) & 1u);
    wv = u1.y; cnt += ((wv >> 7) & 1u) + ((wv >> 23) & 1u);
    wv = u1.z; cnt += ((wv >> 7) & 1u) + ((wv >> 23) & 1u);
    wv = u1.w; cnt += ((wv >> 7) & 1u) + ((wv >> 23) & 1u);
  }
  sde[t] = (float)cnt;
  unsigned short* dst = HbfT + ((size_t)(b * E_ + e0 + er) << 12) + n0 + nc;
  *(uint4*)dst = u0;
  *(uint4*)(dst + 8) = u1;
  __syncthreads();
  if (t < 64) {
    float de = sde[t * 4] + sde[t * 4 + 1] + sde[t * 4 + 2] + sde[t * 4 + 3];
    atomicAdd(&deg_e[b * E_ + e0 + t], de);
  }
}

// ---------------------------------------------------------------------------
// K3 (phase A GEMM): heT_raw[o][e] = sum_n xtT[o][n] * HbfT[e][n]
// K(=n) split x2 across blocks -> p0/p1 fp32 partials. 256 blocks.
// Block: 64o x 64e, BK=64. Both tiles via global_load_lds (XOR chunk swizzle).
// ---------------------------------------------------------------------------
__global__ __launch_bounds__(256) void k_edge(
    const unsigned short* __restrict__ xtT, const unsigned short* __restrict__ HbfT,
    float* __restrict__ p0, float* __restrict__ p1) {
  __shared__ unsigned short ldsA[4096];  // [o-row][k] 64x64, chunk-swizzled
  __shared__ unsigned short ldsB[4096];  // [e-row][k] 64x64, chunk-swizzled
  int t = threadIdx.x;
  int ks = blockIdx.x & 1, et = (blockIdx.x >> 1) & 31, b = blockIdx.x >> 6;
  int e0 = et * 64;
  int w = t >> 6, lane = t & 63, quad = lane >> 4, m15 = lane & 15;

  // staging: thread covers linear chunks i0,i1; fetch global chunk that maps there
  int i0 = w * 128 + lane, i1 = i0 + 64;
  int row0 = i0 >> 3, cc0 = (i0 & 7) ^ (row0 & 7);
  int row1 = i1 >> 3, cc1 = (i1 & 7) ^ (row1 & 7);
  int gOff0 = row0 * 4096 + cc0 * 8;  // ushort units (both sources stride 4096)
  int gOff1 = row1 * 4096 + cc1 * 8;
  char* lA = (char*)ldsA; char* lB = (char*)ldsB;
  int lOff0 = i0 * 16, lOff1 = i1 * 16;

  const unsigned short* gA = xtT + ((size_t)b << 18) + ks * 2048;
  const unsigned short* gB = HbfT + (((size_t)(b * E_ + e0)) << 12) + ks * 2048;

  // fragment read offsets (row&7 == m15&7 for all tiles used)
  int xr = m15 & 7;
  int aBase = (w * 16 + m15) * 128;
  int fs0 = (quad ^ xr) * 16, fs1 = ((4 + quad) ^ xr) * 16;

  float4v acc[4];
#pragma unroll
  for (int ct = 0; ct < 4; ++ct) acc[ct] = (float4v){0.f, 0.f, 0.f, 0.f};

  for (int kt = 0; kt < 32; ++kt) {
    stage16(gA + gOff0, lA + lOff0);
    stage16(gA + gOff1, lA + lOff1);
    stage16(gB + gOff0, lB + lOff0);
    stage16(gB + gOff1, lB + lOff1);
    __syncthreads();
#pragma unroll
    for (int s = 0; s < 2; ++s) {
      int fo = s ? fs1 : fs0;
      short8 a = *(const short8*)(lA + aBase + fo);
#pragma unroll
      for (int ct = 0; ct < 4; ++ct) {
        short8 bb = *(const short8*)(lB + (ct * 16 + m15) * 128 + fo);
        acc[ct] = __builtin_amdgcn_mfma_f32_16x16x32_bf16(a, bb, acc[ct], 0, 0, 0);
      }
    }
    __syncthreads();
    gA += 64; gB += 64;
  }
  float* dst = ks ? p1 : p0;
#pragma unroll
  for (int ct = 0; ct < 4; ++ct)
#pragma unroll
    for (int r = 0; r < 4; ++r) {
      int o = w * 16 + quad * 4 + r;
      dst[((size_t)(b * 64 + o)) * E_ + e0 + ct * 16 + m15] = acc[ct][r];
    }
}

// ---------------------------------------------------------------------------
// K4: heT[b][o][e] = bf16( (p0+p1) / deg_e[b][e] )
// ---------------------------------------------------------------------------
__global__ __launch_bounds__(256) void k_henorm(
    const float* __restrict__ p0, const float* __restrict__ p1,
    const float* __restrict__ deg_e, unsigned short* __restrict__ heT) {
  int idx = (blockIdx.x * 256 + threadIdx.x) * 4;
  int e = idx & (E_ - 1);
  int bb = idx >> 17;  // / (64*E_)
  float4 a = *(const float4*)(p0 + idx);
  float4 c = *(const float4*)(p1 + idx);
  float4 d = *(const float4*)(deg_e + bb * E_ + e);
  unsigned int lo = (unsigned int)f2bf((a.x + c.x) / d.x) |
                    ((unsigned int)f2bf((a.y + c.y) / d.y) << 16);
  unsigned int hi = (unsigned int)f2bf((a.z + c.z) / d.z) |
                    ((unsigned int)f2bf((a.w + c.w) / d.w) << 16);
  uint2 u; u.x = lo; u.y = hi;
  *(uint2*)(heT + idx) = u;
}

// ---------------------------------------------------------------------------
// K5 (phase B GEMM): out[n][o] = (sum_e H[n][e]*heT[o][e]) / deg_n[n] + bias[o]
// A-tile staged from fp32 H with inline cvt + swizzled ds_write_b128
// (conflict-free); deg_n computed locally from the same staging reads.
// 256 blocks: 64n x 64o each, full K=2048.
// ---------------------------------------------------------------------------
__global__ __launch_bounds__(256) void k_node(
    const float* __restrict__ H, const unsigned short* __restrict__ heT,
    const float* __restrict__ bias, float* __restrict__ out) {
  __shared__ unsigned short ldsA[4096];  // [n-row][k=e] 64x64 swizzled
  __shared__ unsigned short ldsB[4096];  // [o-row][k=e] 64x64 swizzled
  __shared__ float ldsDn[64];
  int t = threadIdx.x;
  int mt = blockIdx.x & 63, b = blockIdx.x >> 6;
  int n0 = mt * 64;
  int w = t >> 6, lane = t & 63, quad = lane >> 4, m15 = lane & 15;
  if (t < 64) ldsDn[t] = 0.f;

  // B staging (heT rows, stride 2048 ushorts) via global_load_lds
  int i0 = w * 128 + lane, i1 = i0 + 64;
  int row0 = i0 >> 3, cc0 = (i0 & 7) ^ (row0 & 7);
  int row1 = i1 >> 3, cc1 = (i1 & 7) ^ (row1 & 7);
  int gOffB0 = row0 * 2048 + cc0 * 8, gOffB1 = row1 * 2048 + cc1 * 8;
  const unsigned short* gB = heT + ((size_t)b << 17);
  char* lA = (char*)ldsA; char* lB = (char*)ldsB;
  int lOff0 = i0 * 16, lOff1 = i1 * 16;

  // A staging: thread = row lane, 64 B (16 fp32) at quarter w
  const float* gA = H + ((size_t)(b * N_ + n0 + lane)) * E_ + w * 16;
  int aw0 = lane * 128 + ((w * 2) ^ (lane & 7)) * 16;
  int aw1 = lane * 128 + ((w * 2 + 1) ^ (lane & 7)) * 16;

  int xr = m15 & 7;
  int aBase = (w * 16 + m15) * 128;
  int fs0 = (quad ^ xr) * 16, fs1 = ((4 + quad) ^ xr) * 16;

  float dn = 0.f;
  float4v acc[4];
#pragma unroll
  for (int ct = 0; ct < 4; ++ct) acc[ct] = (float4v){0.f, 0.f, 0.f, 0.f};

  for (int kt = 0; kt < 32; ++kt) {
    float4 f0 = *(const float4*)(gA);
    float4 f1 = *(const float4*)(gA + 4);
    float4 f2 = *(const float4*)(gA + 8);
    float4 f3 = *(const float4*)(gA + 12);
    dn += (f0.x + f0.y + f0.z + f0.w) + (f1.x + f1.y + f1.z + f1.w) +
          (f2.x + f2.y + f2.z + f2.w) + (f3.x + f3.y + f3.z + f3.w);
    short8 pa, pb;
    pa[0] = (short)f2bf(f0.x); pa[1] = (short)f2bf(f0.y);
    pa[2] = (short)f2bf(f0.z); pa[3] = (short)f2bf(f0.w);
    pa[4] = (short)f2bf(f1.x); pa[5] = (short)f2bf(f1.y);
    pa[6] = (short)f2bf(f1.z); pa[7] = (short)f2bf(f1.w);
    pb[0] = (short)f2bf(f2.x); pb[1] = (short)f2bf(f2.y);
    pb[2] = (short)f2bf(f2.z); pb[3] = (short)f2bf(f2.w);
    pb[4] = (short)f2bf(f3.x); pb[5] = (short)f2bf(f3.y);
    pb[6] = (short)f2bf(f3.z); pb[7] = (short)f2bf(f3.w);
    *(short8*)(lA + aw0) = pa;
    *(short8*)(lA + aw1) = pb;
    stage16(gB + gOffB0, lB + lOff0);
    stage16(gB + gOffB1, lB + lOff1);
    __syncthreads();
#pragma unroll
    for (int s = 0; s < 2; ++s) {
      int fo = s ? fs1 : fs0;
      short8 a = *(const short8*)(lA + aBase + fo);
#pragma unroll
      for (int ct = 0; ct < 4; ++ct) {
        short8 bb = *(const short8*)(lB + (ct * 16 + m15) * 128 + fo);
        acc[ct] = __builtin_amdgcn_mfma_f32_16x16x32_bf16(a, bb, acc[ct], 0, 0, 0);
      }
    }
    __syncthreads();
    gA += 64; gB += 64;
  }
  atomicAdd(&ldsDn[lane], dn);
  __syncthreads();
  float bv[4];
#pragma unroll
  for (int ct = 0; ct < 4; ++ct) bv[ct] = bias[ct * 16 + m15];
#pragma unroll
  for (int r = 0; r < 4; ++r) {
    int row = w * 16 + quad * 4 + r;
    float inv = 1.0f / ldsDn[row];
    int n = n0 + row;
#pragma unroll
    for (int ct = 0; ct < 4; ++ct)
      out[(((size_t)(b * N_ + n)) << 6) + ct * 16 + m15] = acc[ct][r] * inv + bv[ct];
  }
}

extern "C" void kernel_launch(void* const* d_in, const int* in_sizes, int n_in,
                              void* d_out, int out_size, void* d_ws, size_t ws_size,
                              hipStream_t stream) {
  const float* x     = (const float*)d_in[0];
  const float* H     = (const float*)d_in[1];
  const float* theta = (const float*)d_in[2];
  const float* bias  = (const float*)d_in[3];

  // ws: HbfT 64MB | xtT 2MB | p0 2MB | p1 2MB | heT 1MB | deg_e 32KB  (~71.5MB)
  char* ws = (char*)d_ws;
  unsigned short* HbfT = (unsigned short*)ws;
  unsigned short* xtT  = (unsigned short*)(ws + 67108864);
  float* p0            = (float*)(ws + 69206016);
  float* p1            = (float*)(ws + 71303168);
  unsigned short* heT  = (unsigned short*)(ws + 73400320);
  float* deg_e         = (float*)(ws + 74448896);

  hipMemsetAsync(deg_e, 0, B_ * E_ * sizeof(float), stream);
  k_transform<<<256, 256, 0, stream>>>(x, theta, xtT);
  k_prep<<<8192, 256, 0, stream>>>(H, HbfT, deg_e);
  k_edge<<<256, 256, 0, stream>>>(xtT, HbfT, p0, p1);
  k_henorm<<<512, 256, 0, stream>>>(p0, p1, deg_e, heT);
  k_node<<<256, 256, 0, stream>>>(H, heT, bias, (float*)d_out);
}

// Round 4
// 254.871 us; speedup vs baseline: 3.0962x; 1.1634x over previous
//
#include <hip/hip_runtime.h>

// B=4, N=4096, E=2048, C=64.
// Pipeline: k_transform (xtT bf16) -> k_edge (fused H-transpose + deg_e +
// GEMM heT partials, K-split x4 over N=4096 -> 1024 each) -> k_henorm
// (combine+normalize -> heT bf16) -> k_node (GEMM out partials + deg_n,
// K-split x4 over E=2048 -> 512 each) -> k_final (combine).
#define B_ 4
#define N_ 4096
#define E_ 2048

typedef __attribute__((ext_vector_type(8))) short short8;   // 8 bf16
typedef __attribute__((ext_vector_type(4))) float float4v;  // MFMA C/D

// round-to-nearest-even f32 -> bf16 bits
static __device__ __forceinline__ unsigned short f2bf(float f) {
  union { float f; unsigned int u; } v; v.f = f;
  unsigned int r = (v.u + 0x7FFFu + ((v.u >> 16) & 1u)) >> 16;
  return (unsigned short)r;
}

// async global->LDS, 16 B per lane; LDS dest = wave-uniform base + lane*16
static __device__ __forceinline__ void stage16(const void* g, void* l) {
  __builtin_amdgcn_global_load_lds(
      (const __attribute__((address_space(1))) unsigned int*)g,
      (__attribute__((address_space(3))) unsigned int*)l, 16, 0, 0);
}

// ---------------------------------------------------------------------------
// K1: xtT[b][o][n] = bf16( sum_k x[b][n][k] * theta[k][o] )   (transposed)
// ---------------------------------------------------------------------------
__global__ __launch_bounds__(256) void k_transform(
    const float* __restrict__ x, const float* __restrict__ theta,
    unsigned short* __restrict__ xtT) {
  __shared__ unsigned short ldsT[64][72];
  int t = threadIdx.x;
  int nt = blockIdx.x & 63, b = blockIdx.x >> 6;
  int n0 = nt * 64;
  int o = t & 63, nq = t >> 6;
#pragma unroll 4
  for (int i = 0; i < 16; ++i) {
    int n = n0 + nq * 16 + i;
    const float* xr = x + ((size_t)(b * N_ + n) << 6);
    float acc = 0.f;
#pragma unroll
    for (int k = 0; k < 64; ++k) acc += xr[k] * theta[k * 64 + o];
    ldsT[o][nq * 16 + i] = f2bf(acc);
  }
  __syncthreads();
  int orow = t >> 2, c = (t & 3) * 16;
  unsigned short* dst = xtT + ((size_t)(b * 64 + orow) << 12) + n0 + c;
  *(uint4*)dst = *(const uint4*)&ldsT[orow][c];
  *(uint4*)(dst + 8) = *(const uint4*)&ldsT[orow][c + 8];
}

// ---------------------------------------------------------------------------
// K2 (phase A GEMM, fused transpose): for K-chunk ks (1024 n each, x4):
//   p_he[ks][b][o][e] = sum_{n in chunk} xtT[o][n] * H[n][e]
//   deg_e_part[ks][b][e] = sum_{n in chunk} H[n][e]
// grid 512 = b(4) x e-tile(32) x ks(4); block 64o x 64e, BK=64.
// A staged via global_load_lds (XOR chunk swizzle). B staged by transposing
// fp32 H on the fly: lane=e reads 16 n-rows coalesced (256B/instr), cvt,
// 2x ds_write_b128 into padded [e][72] rows (144B stride, conflict-free).
// ---------------------------------------------------------------------------
__global__ __launch_bounds__(256) void k_edge(
    const unsigned short* __restrict__ xtT, const float* __restrict__ H,
    float* __restrict__ p_he, float* __restrict__ deg_e_part) {
  __shared__ unsigned short ldsA[4096];     // [o-row][k=n] 64x64, chunk-swizzled
  __shared__ unsigned short ldsB[64 * 72];  // [e-row][n] 64x72 padded
  __shared__ float ldsDe[64];
  int t = threadIdx.x;
  int ks = blockIdx.x & 3, et = (blockIdx.x >> 2) & 31, b = blockIdx.x >> 7;
  int e0 = et * 64;
  int w = t >> 6, lane = t & 63, quad = lane >> 4, m15 = lane & 15;
  if (t < 64) ldsDe[t] = 0.f;

  // A staging chunks (xtT rows, stride 4096 shorts)
  int i0 = w * 128 + lane, i1 = i0 + 64;
  int row0 = i0 >> 3, cc0 = (i0 & 7) ^ (row0 & 7);
  int row1 = i1 >> 3, cc1 = (i1 & 7) ^ (row1 & 7);
  int gOff0 = row0 * 4096 + cc0 * 8;
  int gOff1 = row1 * 4096 + cc1 * 8;
  char* lA = (char*)ldsA; char* lB = (char*)ldsB;
  int lOff0 = i0 * 16, lOff1 = i1 * 16;

  const unsigned short* gA = xtT + ((size_t)b << 18) + ks * 1024;
  // B transpose source: lane = e_local, wave w = n-subgroup of 16
  const float* gH = H + ((size_t)(b * N_ + ks * 1024 + w * 16)) * E_ + e0 + lane;

  int xr = m15 & 7;
  int aBase = (w * 16 + m15) * 128;
  int fs0 = (quad ^ xr) * 16, fs1 = ((4 + quad) ^ xr) * 16;
  int bw = lane * 144 + w * 32;  // B write base (bytes)

  float de = 0.f;
  float4v acc[4];
#pragma unroll
  for (int ct = 0; ct < 4; ++ct) acc[ct] = (float4v){0.f, 0.f, 0.f, 0.f};

  for (int kt = 0; kt < 16; ++kt) {
    stage16(gA + gOff0, lA + lOff0);
    stage16(gA + gOff1, lA + lOff1);
    float hv[16];
#pragma unroll
    for (int i = 0; i < 16; ++i) hv[i] = gH[(size_t)i * E_];
#pragma unroll
    for (int i = 0; i < 16; ++i) de += hv[i];
    short8 pa, pb;
#pragma unroll
    for (int i = 0; i < 8; ++i) pa[i] = (short)f2bf(hv[i]);
#pragma unroll
    for (int i = 0; i < 8; ++i) pb[i] = (short)f2bf(hv[8 + i]);
    *(short8*)(lB + bw) = pa;
    *(short8*)(lB + bw + 16) = pb;
    __syncthreads();
#pragma unroll
    for (int s = 0; s < 2; ++s) {
      int fo = s ? fs1 : fs0;
      short8 a = *(const short8*)(lA + aBase + fo);
#pragma unroll
      for (int ct = 0; ct < 4; ++ct) {
        short8 bb =
            *(const short8*)(lB + (ct * 16 + m15) * 144 + s * 64 + quad * 16);
        acc[ct] = __builtin_amdgcn_mfma_f32_16x16x32_bf16(a, bb, acc[ct], 0, 0, 0);
      }
    }
    __syncthreads();
    gA += 64;
    gH += (size_t)64 * E_;
  }
  atomicAdd(&ldsDe[lane], de);
  __syncthreads();
  if (t < 64) deg_e_part[ks * (B_ * E_) + b * E_ + e0 + t] = ldsDe[t];
  float* dst = p_he + (size_t)ks * (B_ * 64 * E_);
#pragma unroll
  for (int ct = 0; ct < 4; ++ct)
#pragma unroll
    for (int r = 0; r < 4; ++r) {
      int o = w * 16 + quad * 4 + r;
      dst[((size_t)(b * 64 + o)) * E_ + e0 + ct * 16 + m15] = acc[ct][r];
    }
}

// ---------------------------------------------------------------------------
// K3: heT[b][o][e] = bf16( (sum_ks p_he[ks]) / (sum_ks deg_e_part[ks]) )
// ---------------------------------------------------------------------------
__global__ __launch_bounds__(256) void k_henorm(
    const float* __restrict__ p_he, const float* __restrict__ deg_e_part,
    unsigned short* __restrict__ heT) {
  int idx = (blockIdx.x * 256 + threadIdx.x) * 4;  // over B*64*E = 524288
  int e = idx & (E_ - 1);
  int b = idx >> 17;
  float4 s = *(const float4*)(p_he + idx);
  float4 d = *(const float4*)(deg_e_part + b * E_ + e);
#pragma unroll
  for (int k = 1; k < 4; ++k) {
    float4 sk = *(const float4*)(p_he + (size_t)k * (B_ * 64 * E_) + idx);
    float4 dk = *(const float4*)(deg_e_part + k * (B_ * E_) + b * E_ + e);
    s.x += sk.x; s.y += sk.y; s.z += sk.z; s.w += sk.w;
    d.x += dk.x; d.y += dk.y; d.z += dk.z; d.w += dk.w;
  }
  unsigned int lo = (unsigned int)f2bf(s.x / d.x) |
                    ((unsigned int)f2bf(s.y / d.y) << 16);
  unsigned int hi = (unsigned int)f2bf(s.z / d.z) |
                    ((unsigned int)f2bf(s.w / d.w) << 16);
  uint2 u; u.x = lo; u.y = hi;
  *(uint2*)(heT + idx) = u;
}

// ---------------------------------------------------------------------------
// K4 (phase B GEMM): for K-chunk ks (512 e each, x4):
//   q[ks][b][n][o] = sum_{e in chunk} H[n][e] * heT[o][e]
//   deg_n_part[ks][b][n] = sum_{e in chunk} H[n][e]
// grid 1024 = b(4) x n-tile(64) x ks(4); block 64n x 64o, BK=64.
// ---------------------------------------------------------------------------
__global__ __launch_bounds__(256) void k_node(
    const float* __restrict__ H, const unsigned short* __restrict__ heT,
    float* __restrict__ q, float* __restrict__ deg_n_part) {
  __shared__ unsigned short ldsA[4096];  // [n-row][k=e] swizzled
  __shared__ unsigned short ldsB[4096];  // [o-row][k=e] swizzled
  __shared__ float ldsDn[64];
  int t = threadIdx.x;
  int ks = blockIdx.x & 3, mt = (blockIdx.x >> 2) & 63, b = blockIdx.x >> 8;
  int n0 = mt * 64;
  int w = t >> 6, lane = t & 63, quad = lane >> 4, m15 = lane & 15;
  if (t < 64) ldsDn[t] = 0.f;

  // B staging (heT rows, stride 2048 shorts)
  int i0 = w * 128 + lane, i1 = i0 + 64;
  int row0 = i0 >> 3, cc0 = (i0 & 7) ^ (row0 & 7);
  int row1 = i1 >> 3, cc1 = (i1 & 7) ^ (row1 & 7);
  int gOffB0 = row0 * 2048 + cc0 * 8, gOffB1 = row1 * 2048 + cc1 * 8;
  const unsigned short* gB = heT + ((size_t)b << 17) + ks * 512;
  char* lA = (char*)ldsA; char* lB = (char*)ldsB;
  int lOff0 = i0 * 16, lOff1 = i1 * 16;

  // A staging: lane = n-row, wave w = 16-float quarter of BK
  const float* gA = H + ((size_t)(b * N_ + n0 + lane)) * E_ + ks * 512 + w * 16;
  int aw0 = lane * 128 + ((w * 2) ^ (lane & 7)) * 16;
  int aw1 = lane * 128 + ((w * 2 + 1) ^ (lane & 7)) * 16;

  int xr = m15 & 7;
  int aBase = (w * 16 + m15) * 128;
  int fs0 = (quad ^ xr) * 16, fs1 = ((4 + quad) ^ xr) * 16;

  float dn = 0.f;
  float4v acc[4];
#pragma unroll
  for (int ct = 0; ct < 4; ++ct) acc[ct] = (float4v){0.f, 0.f, 0.f, 0.f};

  for (int kt = 0; kt < 8; ++kt) {
    float4 f0 = *(const float4*)(gA);
    float4 f1 = *(const float4*)(gA + 4);
    float4 f2 = *(const float4*)(gA + 8);
    float4 f3 = *(const float4*)(gA + 12);
    dn += (f0.x + f0.y + f0.z + f0.w) + (f1.x + f1.y + f1.z + f1.w) +
          (f2.x + f2.y + f2.z + f2.w) + (f3.x + f3.y + f3.z + f3.w);
    short8 pa, pb;
    pa[0] = (short)f2bf(f0.x); pa[1] = (short)f2bf(f0.y);
    pa[2] = (short)f2bf(f0.z); pa[3] = (short)f2bf(f0.w);
    pa[4] = (short)f2bf(f1.x); pa[5] = (short)f2bf(f1.y);
    pa[6] = (short)f2bf(f1.z); pa[7] = (short)f2bf(f1.w);
    pb[0] = (short)f2bf(f2.x); pb[1] = (short)f2bf(f2.y);
    pb[2] = (short)f2bf(f2.z); pb[3] = (short)f2bf(f2.w);
    pb[4] = (short)f2bf(f3.x); pb[5] = (short)f2bf(f3.y);
    pb[6] = (short)f2bf(f3.z); pb[7] = (short)f2bf(f3.w);
    *(short8*)(lA + aw0) = pa;
    *(short8*)(lA + aw1) = pb;
    stage16(gB + gOffB0, lB + lOff0);
    stage16(gB + gOffB1, lB + lOff1);
    __syncthreads();
#pragma unroll
    for (int s = 0; s < 2; ++s) {
      int fo = s ? fs1 : fs0;
      short8 a = *(const short8*)(lA + aBase + fo);
#pragma unroll
      for (int ct = 0; ct < 4; ++ct) {
        short8 bb = *(const short8*)(lB + (ct * 16 + m15) * 128 + fo);
        acc[ct] = __builtin_amdgcn_mfma_f32_16x16x32_bf16(a, bb, acc[ct], 0, 0, 0);
      }
    }
    __syncthreads();
    gA += 64; gB += 64;
  }
  atomicAdd(&ldsDn[lane], dn);
  __syncthreads();
  if (t < 64) deg_n_part[ks * (B_ * N_) + b * N_ + n0 + t] = ldsDn[t];
  float* dst = q + (size_t)ks * ((size_t)B_ * N_ * 64);
#pragma unroll
  for (int r = 0; r < 4; ++r) {
    int row = w * 16 + quad * 4 + r;
    int n = n0 + row;
#pragma unroll
    for (int ct = 0; ct < 4; ++ct)
      dst[(((size_t)(b * N_ + n)) << 6) + ct * 16 + m15] = acc[ct][r];
  }
}

// ---------------------------------------------------------------------------
// K5: out[b][n][o] = (sum_ks q[ks]) / (sum_ks deg_n_part[ks]) + bias[o]
// ---------------------------------------------------------------------------
__global__ __launch_bounds__(256) void k_final(
    const float* __restrict__ q, const float* __restrict__ deg_n_part,
    const float* __restrict__ bias, float* __restrict__ out) {
  int idx = (blockIdx.x * 256 + threadIdx.x) * 4;  // over B*N*64 = 1048576
  int o = idx & 63;
  int bn = idx >> 6;
  float4 s = *(const float4*)(q + idx);
  float dn = deg_n_part[bn];
#pragma unroll
  for (int k = 1; k < 4; ++k) {
    float4 sk = *(const float4*)(q + (size_t)k * ((size_t)B_ * N_ * 64) + idx);
    s.x += sk.x; s.y += sk.y; s.z += sk.z; s.w += sk.w;
    dn += deg_n_part[k * (B_ * N_) + bn];
  }
  float4 bv = *(const float4*)(bias + o);
  float inv = 1.0f / dn;
  float4 r;
  r.x = s.x * inv + bv.x; r.y = s.y * inv + bv.y;
  r.z = s.z * inv + bv.z; r.w = s.w * inv + bv.w;
  *(float4*)(out + idx) = r;
}

extern "C" void kernel_launch(void* const* d_in, const int* in_sizes, int n_in,
                              void* d_out, int out_size, void* d_ws, size_t ws_size,
                              hipStream_t stream) {
  const float* x     = (const float*)d_in[0];
  const float* H     = (const float*)d_in[1];
  const float* theta = (const float*)d_in[2];
  const float* bias  = (const float*)d_in[3];

  // ws layout (bytes):
  // xtT 2MB | p_he 8MB | heT 1MB | deg_e_part 128KB | q 16MB | deg_n_part 256KB
  char* ws = (char*)d_ws;
  unsigned short* xtT  = (unsigned short*)ws;
  float* p_he          = (float*)(ws + 2097152);
  unsigned short* heT  = (unsigned short*)(ws + 10485760);
  float* deg_e_part    = (float*)(ws + 11534336);
  float* q             = (float*)(ws + 12582912);
  float* deg_n_part    = (float*)(ws + 29360128);

  k_transform<<<256, 256, 0, stream>>>(x, theta, xtT);
  k_edge<<<512, 256, 0, stream>>>(xtT, H, p_he, deg_e_part);
  k_henorm<<<512, 256, 0, stream>>>(p_he, deg_e_part, heT);
  k_node<<<1024, 256, 0, stream>>>(H, heT, q, deg_n_part);
  k_final<<<1024, 256, 0, stream>>>(q, deg_n_part, bias, (float*)d_out);
}